// Round 7
// baseline (27616.223 us; speedup 1.0000x reference)
//
#include <hip/hip_runtime.h>
#include <math.h>

// Sinkhorn OT layer, B=8192, C=256, L=100, LAMBD=1.
//
// U = log_u - ||x_i||^2, V = log_v - ||y_j||^2, G[i][j] = 2*dot(x_i,y_j):
//   U[i] = -LSE_j(G[i][j] + V[j]),  V[j] = -LSE_i(G[i][j] + U[i])
// init V[j] = -||y_j||^2. Final: out[i] = y[argmax_j(G[i][j]+V[j])].
//
// R6: int24 G (Glo u16 + Ghi s8), separate passes: 7498 us.
// R7/R9 cache re-read fusion: FAILED. R10 LDS-atomic fusion: DISASTER.
// R11: register-resident fusion (thread owns 16 cols, val[] survives the
// block row-reduce, 1 exp/element, G read once/iter): 4930 us. WIN.
// R12: two orthogonal fixes:
//  1. fused_iter software pipelining: prefetch window w+1's raw G bytes
//     into named regs BEFORE window w's reductions (loads in flight
//     across the barrier), and ONE barrier per window: wave publishes
//     (Mw, sw=sum exp(val-Mw)); after the barrier each thread recombines
//     globally: M=max Mw, S=sum sw*exp(Mw-M), scale f=exp(Mw-M)/S,
//     cs[k] += val[k]*f. Double-buffered publish slots (w+2 writes after
//     barrier w+1 > last read of slot at barrier w+1: safe).
//  2. GEMM re-tile 64x64/(4x4) -> 128x64/(8x4): 128 FMA per 12 LDS-b128
//     (vs 64/8) -- half the LDS/issue overhead per FLOP.
//
// Kept: int24 G (q=2^-15, err 1.5e-5), linear column sums of
// P=exp(G+V-W) in [0,1], combine clamp, smallest-index argmax tie-break.

#define B 8192
#define C 256
#define LITERS 100
#define RPB 16                     // rows per fused block
#define NCH (B / RPB)              // 512 chunks

#define QS 65536.0f                // (2*acc) * 32768 == acc * 65536
#define QI 3.0517578125e-5f        // 2^-15

typedef float f32x4 __attribute__((ext_vector_type(4)));
typedef unsigned short u16x8 __attribute__((ext_vector_type(8)));
typedef signed char i8x16 __attribute__((ext_vector_type(16)));
typedef signed char i8x8 __attribute__((ext_vector_type(8)));

__device__ __align__(16) float g_V[B];

// ---------------- init: V[j] = -||y_j||^2 ----------------
__global__ __launch_bounds__(256) void init_V(const float* __restrict__ y) {
    int wave = threadIdx.x >> 6;
    int lane = threadIdx.x & 63;
    int row = blockIdx.x * 4 + wave;
    const f32x4* yr = (const f32x4*)(y + (size_t)row * C);
    f32x4 v = yr[lane];
    float s = v.x * v.x + v.y * v.y + v.z * v.z + v.w * v.w;
    #pragma unroll
    for (int off = 32; off; off >>= 1) s += __shfl_down(s, off, 64);
    if (lane == 0) g_V[row] = -s;
}

// ---------------- GEMM: G = 2 * x @ y^T, quantized to int24 ----------------
// 128x64 tile, 256 threads, 8x4 acc/thread, GK=32, LDS stride 36.
#define GM 128
#define GN 64
#define GK 32
#define LST (GK + 4)

__global__ __launch_bounds__(256, 4) void gemm_G(const float* __restrict__ x,
                                                 const float* __restrict__ y,
                                                 unsigned short* __restrict__ Glo,
                                                 signed char* __restrict__ Ghi) {
    __shared__ float As[GM][LST];   // 128 x 36
    __shared__ float Bs[GN][LST];   // 64 x 36
    int bi = blockIdx.y * GM;
    int bj = blockIdx.x * GN;
    int t = threadIdx.x;
    int tx = t & 15, ty = t >> 4;
    float acc[8][4] = {};
    for (int kk = 0; kk < C; kk += GK) {
        #pragma unroll
        for (int l = 0; l < 4; ++l) {      // stage A: 4 float4/thread
            int fid = t + l * 256;         // 0..1023
            int r = fid >> 3;              // 0..127
            int c4 = fid & 7;              // 0..7
            *(f32x4*)&As[r][c4 * 4] =
                *(const f32x4*)(x + (size_t)(bi + r) * C + kk + c4 * 4);
        }
        #pragma unroll
        for (int l = 0; l < 2; ++l) {      // stage B: 2 float4/thread
            int fid = t + l * 256;         // 0..511
            int r = fid >> 3;              // 0..63
            int c4 = fid & 7;
            *(f32x4*)&Bs[r][c4 * 4] =
                *(const f32x4*)(y + (size_t)(bj + r) * C + kk + c4 * 4);
        }
        __syncthreads();
        #pragma unroll
        for (int k4 = 0; k4 < GK / 4; ++k4) {
            f32x4 a[8], b[4];
            #pragma unroll
            for (int ii = 0; ii < 8; ++ii)
                a[ii] = *(const f32x4*)&As[ty * 8 + ii][k4 * 4];
            #pragma unroll
            for (int jj = 0; jj < 4; ++jj)
                b[jj] = *(const f32x4*)&Bs[tx + 16 * jj][k4 * 4];
            #pragma unroll
            for (int ii = 0; ii < 8; ++ii)
                #pragma unroll
                for (int jj = 0; jj < 4; ++jj) {
                    acc[ii][jj] = fmaf(a[ii].x, b[jj].x, acc[ii][jj]);
                    acc[ii][jj] = fmaf(a[ii].y, b[jj].y, acc[ii][jj]);
                    acc[ii][jj] = fmaf(a[ii].z, b[jj].z, acc[ii][jj]);
                    acc[ii][jj] = fmaf(a[ii].w, b[jj].w, acc[ii][jj]);
                }
        }
        __syncthreads();
    }
    #pragma unroll
    for (int ii = 0; ii < 8; ++ii) {
        int gi = bi + ty * 8 + ii;
        #pragma unroll
        for (int jj = 0; jj < 4; ++jj) {
            size_t idx = (size_t)gi * B + bj + tx + 16 * jj;
            float gs = acc[ii][jj] * QS;                       // G * 2^15
            gs = fminf(fmaxf(gs, -8388607.0f), 8388607.0f);    // int24 clamp
            int v = __float2int_rn(gs);
            Glo[idx] = (unsigned short)(v & 0xFFFF);
            Ghi[idx] = (signed char)(v >> 16);
        }
    }
}

// ---------------- fused row+col pass (pipelined, 1 barrier/window) ----------------
// Block = 512 threads (8 waves), owns rows [chunk*16, chunk*16+16).
// Thread t owns cols 16t..16t+15 for every row. Window = 2 rows.

#define LOADW(P, r) { \
    const u16x8* _lp0 = (const u16x8*)(Glo + (size_t)(r) * B); \
    const i8x16* _hp0 = (const i8x16*)(Ghi + (size_t)(r) * B); \
    const u16x8* _lp1 = (const u16x8*)(Glo + (size_t)((r) + 1) * B); \
    const i8x16* _hp1 = (const i8x16*)(Ghi + (size_t)((r) + 1) * B); \
    P##u0a = _lp0[2 * t]; P##u1a = _lp0[2 * t + 1]; P##ha = _hp0[t]; \
    P##u0b = _lp1[2 * t]; P##u1b = _lp1[2 * t + 1]; P##hb = _hp1[t]; \
}

#define PROCW(BUF, P) { \
    float val0[16], val1[16]; \
    _Pragma("unroll") \
    for (int e = 0; e < 8; ++e) { \
        int qa0 = ((int)P##ha[e] << 16) | (int)P##u0a[e]; \
        val0[e] = fmaf((float)qa0, QI, vreg[e]); \
        int qa1 = ((int)P##ha[8 + e] << 16) | (int)P##u1a[e]; \
        val0[8 + e] = fmaf((float)qa1, QI, vreg[8 + e]); \
        int qb0 = ((int)P##hb[e] << 16) | (int)P##u0b[e]; \
        val1[e] = fmaf((float)qb0, QI, vreg[e]); \
        int qb1 = ((int)P##hb[8 + e] << 16) | (int)P##u1b[e]; \
        val1[8 + e] = fmaf((float)qb1, QI, vreg[8 + e]); \
    } \
    float M0 = val0[0], M1 = val1[0]; \
    _Pragma("unroll") \
    for (int k = 1; k < 16; ++k) { M0 = fmaxf(M0, val0[k]); M1 = fmaxf(M1, val1[k]); } \
    _Pragma("unroll") \
    for (int off = 1; off < 64; off <<= 1) { \
        M0 = fmaxf(M0, __shfl_xor(M0, off, 64)); \
        M1 = fmaxf(M1, __shfl_xor(M1, off, 64)); \
    } \
    float s0 = 0.0f, s1 = 0.0f; \
    _Pragma("unroll") \
    for (int k = 0; k < 16; ++k) { \
        val0[k] = __expf(val0[k] - M0); s0 += val0[k]; \
        val1[k] = __expf(val1[k] - M1); s1 += val1[k]; \
    } \
    _Pragma("unroll") \
    for (int off = 1; off < 64; off <<= 1) { \
        s0 += __shfl_xor(s0, off, 64); \
        s1 += __shfl_xor(s1, off, 64); \
    } \
    if (lane == 0) { wm[BUF][0][wave] = M0; ws[BUF][0][wave] = s0; \
                     wm[BUF][1][wave] = M1; ws[BUF][1][wave] = s1; } \
    __syncthreads(); \
    float gM0 = wm[BUF][0][0], gM1 = wm[BUF][1][0]; \
    _Pragma("unroll") \
    for (int k = 1; k < 8; ++k) { \
        gM0 = fmaxf(gM0, wm[BUF][0][k]); \
        gM1 = fmaxf(gM1, wm[BUF][1][k]); \
    } \
    float gS0 = 0.0f, gS1 = 0.0f; \
    _Pragma("unroll") \
    for (int k = 0; k < 8; ++k) { \
        gS0 += ws[BUF][0][k] * __expf(wm[BUF][0][k] - gM0); \
        gS1 += ws[BUF][1][k] * __expf(wm[BUF][1][k] - gM1); \
    } \
    float f0 = __expf(M0 - gM0) / gS0; \
    float f1 = __expf(M1 - gM1) / gS1; \
    _Pragma("unroll") \
    for (int k = 0; k < 16; ++k) { \
        cs[k] = fmaf(val0[k], f0, cs[k]); \
        cs[k] = fmaf(val1[k], f1, cs[k]); \
    } \
}

__global__ __launch_bounds__(512, 4) void fused_iter(
        const unsigned short* __restrict__ Glo,
        const signed char* __restrict__ Ghi,
        float* __restrict__ pm) {
    __shared__ float wm[2][2][8];   // [buf][row][wave]
    __shared__ float ws[2][2][8];
    int t = threadIdx.x;
    int chunk = blockIdx.x;
    int i0 = chunk * RPB;
    int wave = t >> 6, lane = t & 63;

    // this thread's 16 V values (constant across the dispatch)
    float vreg[16];
    #pragma unroll
    for (int q = 0; q < 4; ++q) {
        f32x4 v = *(const f32x4*)&g_V[16 * t + 4 * q];
        vreg[4 * q + 0] = v.x; vreg[4 * q + 1] = v.y;
        vreg[4 * q + 2] = v.z; vreg[4 * q + 3] = v.w;
    }
    float cs[16];
    #pragma unroll
    for (int k = 0; k < 16; ++k) cs[k] = 0.0f;

    // pipelined raw-register double buffer (A = even windows, B = odd)
    u16x8 Au0a, Au1a, Au0b, Au1b; i8x16 Aha, Ahb;
    u16x8 Bu0a, Bu1a, Bu0b, Bu1b; i8x16 Bha, Bhb;

    LOADW(A, i0);                              // window 0
    #pragma unroll
    for (int w = 0; w < RPB / 2; w += 2) {
        LOADW(B, i0 + 2 * (w + 1));            // prefetch odd window
        PROCW(0, A)                            // process even window
        if (w + 2 < RPB / 2) LOADW(A, i0 + 2 * (w + 2));  // prefetch next even
        PROCW(1, B)                            // process odd window
    }

    // ---- writeout ----
    #pragma unroll
    for (int q = 0; q < 4; ++q) {
        f32x4 o = {cs[4 * q + 0], cs[4 * q + 1], cs[4 * q + 2], cs[4 * q + 3]};
        *(f32x4*)&pm[(size_t)chunk * B + 16 * t + 4 * q] = o;
    }
}

// ---------------- combine: V[j] -= log(sum of 512 chunk partials) ----------------
__global__ __launch_bounds__(256) void col_combine(const float* __restrict__ pm) {
    int t = threadIdx.x;
    int pl = t & 31;
    int g = t >> 5;               // 0..7
    int j = blockIdx.x * 32 + pl;
    float s = 0.0f;
    #pragma unroll 8
    for (int c = g * 64; c < g * 64 + 64; ++c)
        s += pm[(size_t)c * B + j];
    __shared__ float ls[8][32];
    ls[g][pl] = s;
    __syncthreads();
    if (t < 32) {
        float s0 = ls[0][t];
        #pragma unroll
        for (int gg = 1; gg < 8; ++gg) s0 += ls[gg][t];
        int jj = blockIdx.x * 32 + t;
        // clamp: all-underflow columns get a bounded push (self-correcting)
        g_V[jj] -= logf(fmaxf(s0, 1e-30f));
    }
}

// ---------------- argmax + gather: out[i] = y[argmax_j(G[i][j]+V[j])] ----------------
__global__ __launch_bounds__(256) void argmax_out(const unsigned short* __restrict__ Glo,
                                                  const signed char* __restrict__ Ghi,
                                                  const float* __restrict__ y,
                                                  float* __restrict__ out) {
    int i = blockIdx.x;
    int t = threadIdx.x;
    const u16x8* lo8 = (const u16x8*)(Glo + (size_t)i * B);
    const i8x8*  hi8 = (const i8x8*)(Ghi + (size_t)i * B);
    const f32x4* v4 = (const f32x4*)g_V;
    float best = -INFINITY;
    int bj = 0;                              // safe init (never OOB)
    #pragma unroll
    for (int it = 0; it < 4; ++it) {
        int idx = it * 256 + t;
        u16x8 lo = lo8[idx];
        i8x8  hi = hi8[idx];
        f32x4 va = v4[idx * 2], vb = v4[idx * 2 + 1];
        float vv[8] = {va.x, va.y, va.z, va.w, vb.x, vb.y, vb.z, vb.w};
        #pragma unroll
        for (int k = 0; k < 8; ++k) {
            int q = ((int)hi[k] << 16) | (int)lo[k];
            float val = fmaf((float)q, QI, vv[k]);
            int j = idx * 8 + k;
            if (val > best) { best = val; bj = j; }
        }
    }
    __shared__ float bm[256];
    __shared__ int   bidx[256];
    bm[t] = best; bidx[t] = bj;
    __syncthreads();
    #pragma unroll
    for (int off = 128; off; off >>= 1) {
        if (t < off) {
            float om = bm[t + off]; int oj = bidx[t + off];
            if (om > bm[t] || (om == bm[t] && oj < bidx[t])) { bm[t] = om; bidx[t] = oj; }
        }
        __syncthreads();
    }
    int jstar = bidx[0];
    out[(size_t)i * C + t] = y[(size_t)jstar * C + t];
}

extern "C" void kernel_launch(void* const* d_in, const int* in_sizes, int n_in,
                              void* d_out, int out_size, void* d_ws, size_t ws_size,
                              hipStream_t stream) {
    const float* x = (const float*)d_in[0];
    const float* y = (const float*)d_in[1];
    float* out = (float*)d_out;
    unsigned short* Glo = (unsigned short*)d_ws;                           // 128 MiB
    signed char*    Ghi = (signed char*)((char*)d_ws + (size_t)B * B * 2); // +64 MiB
    float* pm = (float*)((char*)d_ws + (size_t)B * B * 3);                 // +16 MiB

    init_V<<<B / 4, 256, 0, stream>>>(y);
    gemm_G<<<dim3(B / GN, B / GM), 256, 0, stream>>>(x, y, Glo, Ghi);
    for (int l = 0; l < LITERS; ++l) {
        fused_iter<<<NCH, 512, 0, stream>>>(Glo, Ghi, pm);
        col_combine<<<B / 32, 256, 0, stream>>>(pm);
    }
    argmax_out<<<B, 256, 0, stream>>>(Glo, Ghi, y, out);
}

// Round 8
// 4875.269 us; speedup vs baseline: 5.6646x; 5.6646x over previous
//
#include <hip/hip_runtime.h>
#include <math.h>

// Sinkhorn OT layer, B=8192, C=256, L=100, LAMBD=1.
//
// U = log_u - ||x_i||^2, V = log_v - ||y_j||^2, G[i][j] = 2*dot(x_i,y_j):
//   U[i] = -LSE_j(G[i][j] + V[j]),  V[j] = -LSE_i(G[i][j] + U[i])
// init V[j] = -||y_j||^2. Final: out[i] = y[argmax_j(G[i][j]+V[j])].
//
// R6: int24 G (Glo u16 + Ghi s8), separate passes: 7498 us.
// R11: register-resident fusion (thread owns 16 cols, val[] survives the
// block row-reduce in regs, 1 exp/element, G read once/iter): 4930 us.
// R12 (DISASTER 27616): explicit prefetch double-buffer (+48 live VGPR)
// + 128x64 GEMM (+ live regs) -> both kernels spilled to scratch
// (WRITE_SIZE 505/995 MB per dispatch). REVERTED.
// R13 = R11 structure with zero-register-pressure improvements only:
//  (a) hi bytes as one i8x16 load (was 2x i8x8);
//  (b) ONE barrier per window: wave publishes (Mw, sw) together; each
//      thread recombines globally after the barrier:
//      gM = max Mw, gS = sum sw*exp(Mw-gM), f = exp(Mw-gM)/gS,
//      cs[k] += val[k]*f   (extra ~0.5 exp/element, -8 barriers, -1 LDS
//      round-trip per window; publish slots double-buffered, safe:
//      slot w reused at w+2, fenced by barrier w+1).
// GEMM: R6's proven 64x64 tile (554 us, no spill).
//
// Kept: int24 G (q=2^-15, err 1.5e-5), linear column sums of
// P=exp(G+V-W) in [0,1], combine clamp, smallest-index argmax tie-break.

#define B 8192
#define C 256
#define LITERS 100
#define RPB 16                     // rows per fused block
#define NCH (B / RPB)              // 512 chunks

#define QS 65536.0f                // (2*acc) * 32768 == acc * 65536
#define QI 3.0517578125e-5f        // 2^-15

typedef float f32x4 __attribute__((ext_vector_type(4)));
typedef unsigned short u16x8 __attribute__((ext_vector_type(8)));
typedef signed char i8x16 __attribute__((ext_vector_type(16)));
typedef signed char i8x8 __attribute__((ext_vector_type(8)));

__device__ __align__(16) float g_V[B];

// ---------------- init: V[j] = -||y_j||^2 ----------------
__global__ __launch_bounds__(256) void init_V(const float* __restrict__ y) {
    int wave = threadIdx.x >> 6;
    int lane = threadIdx.x & 63;
    int row = blockIdx.x * 4 + wave;
    const f32x4* yr = (const f32x4*)(y + (size_t)row * C);
    f32x4 v = yr[lane];
    float s = v.x * v.x + v.y * v.y + v.z * v.z + v.w * v.w;
    #pragma unroll
    for (int off = 32; off; off >>= 1) s += __shfl_down(s, off, 64);
    if (lane == 0) g_V[row] = -s;
}

// ---------------- GEMM: G = 2 * x @ y^T, quantized to int24 (R6 version) ----------------
#define GT 64
#define GKT 64
#define LSTR (GKT + 4)   // 68 floats; float4-aligned offsets

__global__ __launch_bounds__(256) void gemm_G(const float* __restrict__ x,
                                              const float* __restrict__ y,
                                              unsigned short* __restrict__ Glo,
                                              signed char* __restrict__ Ghi) {
    __shared__ float As[GT][LSTR];   // [i][k]
    __shared__ float Bs[GT][LSTR];   // [j][k]
    int bi = blockIdx.y * GT;
    int bj = blockIdx.x * GT;
    int t = threadIdx.x;
    int tx = t & 15, ty = t >> 4;
    float acc[4][4] = {};
    for (int kk = 0; kk < C; kk += GKT) {
        #pragma unroll
        for (int l = 0; l < 4; ++l) {
            int idx = t + l * 256;         // float4 index in tile
            int r = idx >> 4;              // tile row 0..63
            int c4 = idx & 15;             // float4 col 0..15
            *(f32x4*)&As[r][c4 * 4] =
                *(const f32x4*)(x + (size_t)(bi + r) * C + kk + c4 * 4);
            *(f32x4*)&Bs[r][c4 * 4] =
                *(const f32x4*)(y + (size_t)(bj + r) * C + kk + c4 * 4);
        }
        __syncthreads();
        #pragma unroll
        for (int k4 = 0; k4 < GKT / 4; ++k4) {
            f32x4 a[4], b[4];
            #pragma unroll
            for (int ii = 0; ii < 4; ++ii)
                a[ii] = *(const f32x4*)&As[ty * 4 + ii][k4 * 4];
            #pragma unroll
            for (int jj = 0; jj < 4; ++jj)
                b[jj] = *(const f32x4*)&Bs[tx + 16 * jj][k4 * 4];
            #pragma unroll
            for (int ii = 0; ii < 4; ++ii)
                #pragma unroll
                for (int jj = 0; jj < 4; ++jj) {
                    acc[ii][jj] = fmaf(a[ii].x, b[jj].x, acc[ii][jj]);
                    acc[ii][jj] = fmaf(a[ii].y, b[jj].y, acc[ii][jj]);
                    acc[ii][jj] = fmaf(a[ii].z, b[jj].z, acc[ii][jj]);
                    acc[ii][jj] = fmaf(a[ii].w, b[jj].w, acc[ii][jj]);
                }
        }
        __syncthreads();
    }
    #pragma unroll
    for (int ii = 0; ii < 4; ++ii) {
        int gi = bi + ty * 4 + ii;
        #pragma unroll
        for (int jj = 0; jj < 4; ++jj) {
            size_t idx = (size_t)gi * B + bj + tx + 16 * jj;
            float gs = acc[ii][jj] * QS;                       // G * 2^15
            gs = fminf(fmaxf(gs, -8388607.0f), 8388607.0f);    // int24 clamp
            int v = __float2int_rn(gs);
            Glo[idx] = (unsigned short)(v & 0xFFFF);
            Ghi[idx] = (signed char)(v >> 16);
        }
    }
}

// ---------------- fused row+col pass (1 barrier/window) ----------------
// Block = 512 threads (8 waves), owns rows [chunk*16, chunk*16+16).
// Thread t owns cols 16t..16t+15 for every row. Window = 2 rows.
__global__ __launch_bounds__(512, 4) void fused_iter(
        const unsigned short* __restrict__ Glo,
        const signed char* __restrict__ Ghi,
        float* __restrict__ pm) {
    __shared__ float wm[2][2][8];   // [buf][row][wave]
    __shared__ float ws[2][2][8];
    int t = threadIdx.x;
    int chunk = blockIdx.x;
    int i0 = chunk * RPB;
    int wave = t >> 6, lane = t & 63;

    // this thread's 16 V values (constant across the dispatch)
    float vreg[16];
    #pragma unroll
    for (int q = 0; q < 4; ++q) {
        f32x4 v = *(const f32x4*)&g_V[16 * t + 4 * q];
        vreg[4 * q + 0] = v.x; vreg[4 * q + 1] = v.y;
        vreg[4 * q + 2] = v.z; vreg[4 * q + 3] = v.w;
    }
    float cs[16];
    #pragma unroll
    for (int k = 0; k < 16; ++k) cs[k] = 0.0f;

    for (int w = 0; w < RPB / 2; ++w) {
        int buf = w & 1;
        int ra = i0 + 2 * w;
        int rb = ra + 1;
        // ---- load both rows' 16 cols: val = G + V ----
        float val0[16], val1[16];
        {
            const u16x8* lop = (const u16x8*)(Glo + (size_t)ra * B);
            const i8x16* hp  = (const i8x16*)(Ghi + (size_t)ra * B);
            u16x8 a0 = lop[2 * t], a1 = lop[2 * t + 1];
            i8x16 h = hp[t];
            #pragma unroll
            for (int e = 0; e < 8; ++e) {
                int q0 = ((int)h[e] << 16) | (int)a0[e];
                val0[e] = fmaf((float)q0, QI, vreg[e]);
                int q1 = ((int)h[8 + e] << 16) | (int)a1[e];
                val0[8 + e] = fmaf((float)q1, QI, vreg[8 + e]);
            }
        }
        {
            const u16x8* lop = (const u16x8*)(Glo + (size_t)rb * B);
            const i8x16* hp  = (const i8x16*)(Ghi + (size_t)rb * B);
            u16x8 a0 = lop[2 * t], a1 = lop[2 * t + 1];
            i8x16 h = hp[t];
            #pragma unroll
            for (int e = 0; e < 8; ++e) {
                int q0 = ((int)h[e] << 16) | (int)a0[e];
                val1[e] = fmaf((float)q0, QI, vreg[e]);
                int q1 = ((int)h[8 + e] << 16) | (int)a1[e];
                val1[8 + e] = fmaf((float)q1, QI, vreg[8 + e]);
            }
        }
        // ---- wave-local max (no exps) ----
        float M0 = val0[0], M1 = val1[0];
        #pragma unroll
        for (int k = 1; k < 16; ++k) {
            M0 = fmaxf(M0, val0[k]);
            M1 = fmaxf(M1, val1[k]);
        }
        #pragma unroll
        for (int off = 1; off < 64; off <<= 1) {
            M0 = fmaxf(M0, __shfl_xor(M0, off, 64));
            M1 = fmaxf(M1, __shfl_xor(M1, off, 64));
        }
        // ---- e = exp(val - Mw) in place; wave-local sum ----
        float s0 = 0.0f, s1 = 0.0f;
        #pragma unroll
        for (int k = 0; k < 16; ++k) {
            val0[k] = __expf(val0[k] - M0); s0 += val0[k];
            val1[k] = __expf(val1[k] - M1); s1 += val1[k];
        }
        #pragma unroll
        for (int off = 1; off < 64; off <<= 1) {
            s0 += __shfl_xor(s0, off, 64);
            s1 += __shfl_xor(s1, off, 64);
        }
        // ---- single publish + single barrier ----
        if (lane == 0) {
            wm[buf][0][wave] = M0; ws[buf][0][wave] = s0;
            wm[buf][1][wave] = M1; ws[buf][1][wave] = s1;
        }
        __syncthreads();
        // ---- per-thread global recombine (redundant, barrier-free) ----
        float gM0 = wm[buf][0][0], gM1 = wm[buf][1][0];
        #pragma unroll
        for (int k = 1; k < 8; ++k) {
            gM0 = fmaxf(gM0, wm[buf][0][k]);
            gM1 = fmaxf(gM1, wm[buf][1][k]);
        }
        float gS0 = 0.0f, gS1 = 0.0f;
        #pragma unroll
        for (int k = 0; k < 8; ++k) {
            gS0 += ws[buf][0][k] * __expf(wm[buf][0][k] - gM0);
            gS1 += ws[buf][1][k] * __expf(wm[buf][1][k] - gM1);
        }
        // scale kept exp(val-Mw) to exp(val-gM)/gS = P in [0,1]
        float f0 = __expf(M0 - gM0) / gS0;
        float f1 = __expf(M1 - gM1) / gS1;
        #pragma unroll
        for (int k = 0; k < 16; ++k) {
            cs[k] = fmaf(val0[k], f0, cs[k]);
            cs[k] = fmaf(val1[k], f1, cs[k]);
        }
    }
    // ---- writeout ----
    #pragma unroll
    for (int q = 0; q < 4; ++q) {
        f32x4 o = {cs[4 * q + 0], cs[4 * q + 1], cs[4 * q + 2], cs[4 * q + 3]};
        *(f32x4*)&pm[(size_t)chunk * B + 16 * t + 4 * q] = o;
    }
}

// ---------------- combine: V[j] -= log(sum of 512 chunk partials) ----------------
__global__ __launch_bounds__(256) void col_combine(const float* __restrict__ pm) {
    int t = threadIdx.x;
    int pl = t & 31;
    int g = t >> 5;               // 0..7
    int j = blockIdx.x * 32 + pl;
    float s = 0.0f;
    #pragma unroll 8
    for (int c = g * 64; c < g * 64 + 64; ++c)
        s += pm[(size_t)c * B + j];
    __shared__ float ls[8][32];
    ls[g][pl] = s;
    __syncthreads();
    if (t < 32) {
        float s0 = ls[0][t];
        #pragma unroll
        for (int gg = 1; gg < 8; ++gg) s0 += ls[gg][t];
        int jj = blockIdx.x * 32 + t;
        // clamp: all-underflow columns get a bounded push (self-correcting)
        g_V[jj] -= logf(fmaxf(s0, 1e-30f));
    }
}

// ---------------- argmax + gather: out[i] = y[argmax_j(G[i][j]+V[j])] ----------------
__global__ __launch_bounds__(256) void argmax_out(const unsigned short* __restrict__ Glo,
                                                  const signed char* __restrict__ Ghi,
                                                  const float* __restrict__ y,
                                                  float* __restrict__ out) {
    int i = blockIdx.x;
    int t = threadIdx.x;
    const u16x8* lo8 = (const u16x8*)(Glo + (size_t)i * B);
    const i8x8*  hi8 = (const i8x8*)(Ghi + (size_t)i * B);
    const f32x4* v4 = (const f32x4*)g_V;
    float best = -INFINITY;
    int bj = 0;                              // safe init (never OOB)
    #pragma unroll
    for (int it = 0; it < 4; ++it) {
        int idx = it * 256 + t;
        u16x8 lo = lo8[idx];
        i8x8  hi = hi8[idx];
        f32x4 va = v4[idx * 2], vb = v4[idx * 2 + 1];
        float vv[8] = {va.x, va.y, va.z, va.w, vb.x, vb.y, vb.z, vb.w};
        #pragma unroll
        for (int k = 0; k < 8; ++k) {
            int q = ((int)hi[k] << 16) | (int)lo[k];
            float val = fmaf((float)q, QI, vv[k]);
            int j = idx * 8 + k;
            if (val > best) { best = val; bj = j; }
        }
    }
    __shared__ float bm[256];
    __shared__ int   bidx[256];
    bm[t] = best; bidx[t] = bj;
    __syncthreads();
    #pragma unroll
    for (int off = 128; off; off >>= 1) {
        if (t < off) {
            float om = bm[t + off]; int oj = bidx[t + off];
            if (om > bm[t] || (om == bm[t] && oj < bidx[t])) { bm[t] = om; bidx[t] = oj; }
        }
        __syncthreads();
    }
    int jstar = bidx[0];
    out[(size_t)i * C + t] = y[(size_t)jstar * C + t];
}

extern "C" void kernel_launch(void* const* d_in, const int* in_sizes, int n_in,
                              void* d_out, int out_size, void* d_ws, size_t ws_size,
                              hipStream_t stream) {
    const float* x = (const float*)d_in[0];
    const float* y = (const float*)d_in[1];
    float* out = (float*)d_out;
    unsigned short* Glo = (unsigned short*)d_ws;                           // 128 MiB
    signed char*    Ghi = (signed char*)((char*)d_ws + (size_t)B * B * 2); // +64 MiB
    float* pm = (float*)((char*)d_ws + (size_t)B * B * 3);                 // +16 MiB

    init_V<<<B / 4, 256, 0, stream>>>(y);
    gemm_G<<<dim3(B / GT, B / GT), 256, 0, stream>>>(x, y, Glo, Ghi);
    for (int l = 0; l < LITERS; ++l) {
        fused_iter<<<NCH, 512, 0, stream>>>(Glo, Ghi, pm);
        col_combine<<<B / 32, 256, 0, stream>>>(pm);
    }
    argmax_out<<<B, 256, 0, stream>>>(Glo, Ghi, y, out);
}